// Round 3
// baseline (136.959 us; speedup 1.0000x reference)
//
#include <hip/hip_runtime.h>

// YOLO decode: 3 scales, B=128, 45 ch = 3 anchors x (iou, dx, dy, dw, dh, 10 cls)
// Output: boxes [NTOT,6] fp32 then mask [NTOT] as 0/1 fp32.
// Round 3: fix decode_vec row index (batch term was dropped in round 2).

constexpr int  BATCH = 128;
constexpr long N13 = 128L * 13 * 13 * 3;   //   64896
constexpr long N26 = 128L * 26 * 26 * 3;   //  259584
constexpr long N52 = 128L * 52 * 52 * 3;   // 1038336
constexpr long NTOT = N13 + N26 + N52;     // 1362816

constexpr int BLOCK = 256;
constexpr int T52 = 128 * 3 * (52 * 52 / 4);   // 259584 threads (4 cells each)
constexpr int T26 = 128 * 3 * (26 * 26 / 4);   //  64896
constexpr int T13 = (int)N13;                  //  64896 (scalar, 1 slot each)
constexpr int B52 = (T52 + BLOCK - 1) / BLOCK; // 1014
constexpr int B26 = (T26 + BLOCK - 1) / BLOCK; //  254
constexpr int B13 = (T13 + BLOCK - 1) / BLOCK; //  254

// ---- vectorized path: one thread = 4 consecutive cells, one anchor ----
template <int H, int STRIDE, long ROWOFF>
__device__ __forceinline__ void decode_vec(const float* __restrict__ o,
                                           const float* __restrict__ anc,
                                           float thresh,
                                           float* __restrict__ out, int tid)
{
    constexpr int hw = H * H;          // divisible by 4 for H=26,52
    constexpr int C4 = hw / 4;
    constexpr int NT = BATCH * 3 * C4;
    if (tid >= NT) return;

    int a = tid % 3;
    int t = tid / 3;
    int chunk = t % C4;
    int b = t / C4;

    const float4* base = (const float4*)o + (b * 45 + a * 15) * C4 + chunk;

    float v[15][4];
#pragma unroll
    for (int j = 0; j < 15; ++j) {
        float4 q = base[j * C4];       // 16B-aligned: C4*16 stride
        v[j][0] = q.x; v[j][1] = q.y; v[j][2] = q.z; v[j][3] = q.w;
    }

    float2 A = ((const float2*)anc)[a];   // anchor (w,h)

    int cell0 = chunk * 4;
    int x = cell0 % H;
    int y = cell0 / H;
    long row = ROWOFF + ((long)b * hw + cell0) * 3 + a;

#pragma unroll
    for (int i = 0; i < 4; ++i) {
        float iou = v[0][i];
        float px = ((float)x + v[1][i]) * (float)STRIDE;
        float py = ((float)y + v[2][i]) * (float)STRIDE;
        float pw = A.x * expf(v[3][i]);
        float ph = A.y * expf(v[4][i]);

        int kind = 0;
        float best = v[5][i];
#pragma unroll
        for (int c = 1; c < 10; ++c)
            if (v[5 + c][i] > best) { best = v[5 + c][i]; kind = c; }

        float2* orow = (float2*)out + row * 3;
        orow[0] = make_float2(iou, px - 0.5f * pw);
        orow[1] = make_float2(py - 0.5f * ph, px + 0.5f * pw);
        orow[2] = make_float2(py + 0.5f * ph, (float)kind);
        out[6 * NTOT + row] = (iou > thresh) ? 1.0f : 0.0f;

        row += 3;
        if (++x == H) { x = 0; ++y; }
    }
}

// ---- scalar path (H=13: hw=169 not 16B-alignable) ----
template <int H, int STRIDE, long ROWOFF>
__device__ __forceinline__ void decode_scalar(const float* __restrict__ o,
                                              const float* __restrict__ anc,
                                              float thresh,
                                              float* __restrict__ out, int tid)
{
    constexpr int hw = H * H;
    constexpr int NT = BATCH * hw * 3;
    if (tid >= NT) return;

    int a = tid % 3;
    int cell = tid / 3;
    int x = (cell % hw) % H;
    int y = (cell % hw) / H;
    int b = cell / hw;

    const float* p = o + (b * 45 + a * 15) * hw + y * H + x;

    float v[15];
#pragma unroll
    for (int j = 0; j < 15; ++j) v[j] = p[j * hw];

    float iou = v[0];
    float px = ((float)x + v[1]) * (float)STRIDE;
    float py = ((float)y + v[2]) * (float)STRIDE;
    float2 A = ((const float2*)anc)[a];
    float pw = A.x * expf(v[3]);
    float ph = A.y * expf(v[4]);

    int kind = 0;
    float best = v[5];
#pragma unroll
    for (int c = 1; c < 10; ++c)
        if (v[5 + c] > best) { best = v[5 + c]; kind = c; }

    long row = ROWOFF + tid;
    float2* orow = (float2*)out + row * 3;
    orow[0] = make_float2(iou, px - 0.5f * pw);
    orow[1] = make_float2(py - 0.5f * ph, px + 0.5f * pw);
    orow[2] = make_float2(py + 0.5f * ph, (float)kind);
    out[6 * NTOT + row] = (iou > thresh) ? 1.0f : 0.0f;
}

__global__ __launch_bounds__(256) void decode_all(
    const float* __restrict__ o13, const float* __restrict__ o26,
    const float* __restrict__ o52, const float* __restrict__ a13,
    const float* __restrict__ a26, const float* __restrict__ a52,
    const float* __restrict__ thr, float* __restrict__ out)
{
    const float thresh = *thr;
    int blk = blockIdx.x;
    if (blk < B52) {
        decode_vec<52, 8, N13 + N26>(o52, a52, thresh, out, blk * BLOCK + (int)threadIdx.x);
    } else if (blk < B52 + B26) {
        decode_vec<26, 16, N13>(o26, a26, thresh, out, (blk - B52) * BLOCK + (int)threadIdx.x);
    } else {
        decode_scalar<13, 32, 0L>(o13, a13, thresh, out, (blk - B52 - B26) * BLOCK + (int)threadIdx.x);
    }
}

extern "C" void kernel_launch(void* const* d_in, const int* in_sizes, int n_in,
                              void* d_out, int out_size, void* d_ws, size_t ws_size,
                              hipStream_t stream) {
    const float* o13 = (const float*)d_in[0];
    const float* o26 = (const float*)d_in[1];
    const float* o52 = (const float*)d_in[2];
    const float* a13 = (const float*)d_in[3];
    const float* a26 = (const float*)d_in[4];
    const float* a52 = (const float*)d_in[5];
    const float* thr = (const float*)d_in[6];
    float* out = (float*)d_out;

    decode_all<<<B52 + B26 + B13, BLOCK, 0, stream>>>(o13, o26, o52, a13, a26, a52, thr, out);
}

// Round 4
// 126.698 us; speedup vs baseline: 1.0810x; 1.0810x over previous
//
#include <hip/hip_runtime.h>

// YOLO decode: 3 scales, B=128, 45 ch = 3 anchors x (iou, dx, dy, dw, dh, 10 cls)
// Output: boxes [NTOT,6] fp32 then mask [NTOT] as 0/1 fp32.
// Round 4: wave-per-anchor mapping, fully contiguous float4 loads, LDS-staged
// fully-coalesced float4 stores. Block = 192 (3 waves). Exact grid division.

constexpr int  BATCH = 128;
constexpr long N13 = 128L * 13 * 13 * 3;   //   64896
constexpr long N26 = 128L * 26 * 26 * 3;   //  259584
constexpr long N52 = 128L * 52 * 52 * 3;   // 1038336
constexpr long NTOT = N13 + N26 + N52;     // 1362816

constexpr int BLOCK = 192;                  // 3 waves: one per anchor
// global-chunk counts (4 cells per chunk), all divisible by 64:
constexpr int GC52 = 128 * (52 * 52 / 4);   // 86528 = 64*1352
constexpr int GC26 = 128 * (26 * 26 / 4);   // 21632 = 64*338
constexpr int B52 = GC52 / 64;              // 1352
constexpr int B26 = GC26 / 64;              // 338
constexpr int B13 = (int)N13 / BLOCK;       // 338 (exact)

// ---- vectorized path: wave = anchor, lane = global chunk (4 cells) ----
template <int H, int STRIDE, long ROWOFF>
__device__ __forceinline__ void decode_vec_lds(const float* __restrict__ o,
                                               const float* __restrict__ anc,
                                               float thresh,
                                               float* __restrict__ out, int blk)
{
    constexpr int hw = H * H;
    constexpr int C4 = hw / 4;

    __shared__ float sbox[768 * 6];   // 18 KB: block's 768 output rows
    __shared__ float smask[768];      //  3 KB

    const int lane = threadIdx.x & 63;
    const int a    = threadIdx.x >> 6;        // 0..2 (wave id = anchor)
    const int gc0  = blk * 64;
    const int gc   = gc0 + lane;              // global chunk id
    const int b    = gc / C4;
    const int chunk = gc % C4;

    const float4* base = (const float4*)o + (long)(b * 45 + a * 15) * C4 + chunk;

    float v[15][4];
#pragma unroll
    for (int j = 0; j < 15; ++j) {
        float4 q = base[(long)j * C4];        // contiguous across lanes per (b,a,j)
        v[j][0] = q.x; v[j][1] = q.y; v[j][2] = q.z; v[j][3] = q.w;
    }

    const float2 A = ((const float2*)anc)[a];

    int cell0 = chunk * 4;
    int x = cell0 % H;
    int y = cell0 / H;
    int lr = lane * 12 + a;                   // local row for i=0

#pragma unroll
    for (int i = 0; i < 4; ++i) {
        float iou = v[0][i];
        float px = ((float)x + v[1][i]) * (float)STRIDE;
        float py = ((float)y + v[2][i]) * (float)STRIDE;
        float pw = A.x * expf(v[3][i]);
        float ph = A.y * expf(v[4][i]);

        int kind = 0;
        float best = v[5][i];
#pragma unroll
        for (int c = 1; c < 10; ++c)
            if (v[5 + c][i] > best) { best = v[5 + c][i]; kind = c; }

        float* r = &sbox[(lr + i * 3) * 6];
        ((float2*)r)[0] = make_float2(iou, px - 0.5f * pw);
        ((float2*)r)[1] = make_float2(py - 0.5f * ph, px + 0.5f * pw);
        ((float2*)r)[2] = make_float2(py + 0.5f * ph, (float)kind);
        smask[lr + i * 3] = (iou > thresh) ? 1.0f : 0.0f;

        if (++x == H) { x = 0; ++y; }
    }

    __syncthreads();

    // boxes: 1152 float4, contiguous, 6 per thread
    const long row0 = ROWOFF + (long)gc0 * 12;
    const float4* sb = (const float4*)sbox;
    float4* ob = (float4*)(out + row0 * 6);
#pragma unroll
    for (int k = 0; k < 6; ++k)
        ob[threadIdx.x + k * BLOCK] = sb[threadIdx.x + k * BLOCK];

    // mask: 192 float4, contiguous, 1 per thread
    float4* om = (float4*)(out + 6 * NTOT + row0);
    om[threadIdx.x] = ((const float4*)smask)[threadIdx.x];
}

// ---- scalar path (H=13: hw=169, not 16B-alignable; 4.8% of slots) ----
template <int H, int STRIDE, long ROWOFF>
__device__ __forceinline__ void decode_scalar(const float* __restrict__ o,
                                              const float* __restrict__ anc,
                                              float thresh,
                                              float* __restrict__ out, int tid)
{
    constexpr int hw = H * H;

    int a = tid % 3;
    int cell = tid / 3;
    int x = (cell % hw) % H;
    int y = (cell % hw) / H;
    int b = cell / hw;

    const float* p = o + (b * 45 + a * 15) * hw + y * H + x;

    float v[15];
#pragma unroll
    for (int j = 0; j < 15; ++j) v[j] = p[j * hw];

    float iou = v[0];
    float px = ((float)x + v[1]) * (float)STRIDE;
    float py = ((float)y + v[2]) * (float)STRIDE;
    float2 A = ((const float2*)anc)[a];
    float pw = A.x * expf(v[3]);
    float ph = A.y * expf(v[4]);

    int kind = 0;
    float best = v[5];
#pragma unroll
    for (int c = 1; c < 10; ++c)
        if (v[5 + c] > best) { best = v[5 + c]; kind = c; }

    long row = ROWOFF + tid;
    float2* orow = (float2*)out + row * 3;
    orow[0] = make_float2(iou, px - 0.5f * pw);
    orow[1] = make_float2(py - 0.5f * ph, px + 0.5f * pw);
    orow[2] = make_float2(py + 0.5f * ph, (float)kind);
    out[6 * NTOT + row] = (iou > thresh) ? 1.0f : 0.0f;
}

__global__ __launch_bounds__(BLOCK) void decode_all(
    const float* __restrict__ o13, const float* __restrict__ o26,
    const float* __restrict__ o52, const float* __restrict__ a13,
    const float* __restrict__ a26, const float* __restrict__ a52,
    const float* __restrict__ thr, float* __restrict__ out)
{
    const float thresh = *thr;
    int blk = blockIdx.x;
    if (blk < B52) {
        decode_vec_lds<52, 8, N13 + N26>(o52, a52, thresh, out, blk);
    } else if (blk < B52 + B26) {
        decode_vec_lds<26, 16, N13>(o26, a26, thresh, out, blk - B52);
    } else {
        decode_scalar<13, 32, 0L>(o13, a13, thresh, out,
                                  (blk - B52 - B26) * BLOCK + (int)threadIdx.x);
    }
}

extern "C" void kernel_launch(void* const* d_in, const int* in_sizes, int n_in,
                              void* d_out, int out_size, void* d_ws, size_t ws_size,
                              hipStream_t stream) {
    const float* o13 = (const float*)d_in[0];
    const float* o26 = (const float*)d_in[1];
    const float* o52 = (const float*)d_in[2];
    const float* a13 = (const float*)d_in[3];
    const float* a26 = (const float*)d_in[4];
    const float* a52 = (const float*)d_in[5];
    const float* thr = (const float*)d_in[6];
    float* out = (float*)d_out;

    decode_all<<<B52 + B26 + B13, BLOCK, 0, stream>>>(o13, o26, o52, a13, a26, a52, thr, out);
}